// Round 8
// baseline (4794.116 us; speedup 1.0000x reference)
//
#include <hip/hip_runtime.h>
#include <hip/hip_bf16.h>

#define LOG2E 1.44269504088896340736f

static __device__ __forceinline__ float sigm(float x){
    return __builtin_amdgcn_rcpf(1.0f + __builtin_amdgcn_exp2f(-LOG2E * x));
}
static __device__ __forceinline__ float tanh_(float x){
    return 2.0f * __builtin_amdgcn_rcpf(1.0f + __builtin_amdgcn_exp2f(-2.0f*LOG2E*x)) - 1.0f;
}

__global__ void marker_kernel(float* out, int n, float v){
    int i = blockIdx.x * 256 + threadIdx.x;
    if (i < n) out[i] = v;
}

// fp32 VALU implementation, f32 outputs (dtype confirmed by round-7 probe decode).
// 1 wave = 16 batch rows; lane l: unit u=l&31, batch-half bh=l>>5 (8 rows each).
// Weights in VGPRs, h broadcast via per-wave LDS slice.
__global__ __launch_bounds__(256, 1)
void vae_f32_kernel(const float* __restrict__ x,      const float* __restrict__ eps,
                    const float* __restrict__ eWih,   const float* __restrict__ eWhh,
                    const float* __restrict__ ebih,   const float* __restrict__ ebhh,
                    const float* __restrict__ Wmu,    const float* __restrict__ bmu,
                    const float* __restrict__ Wlv,    const float* __restrict__ blv,
                    const float* __restrict__ Wl2h,   const float* __restrict__ bl2h,
                    const float* __restrict__ Wl2h2,  const float* __restrict__ bl2h2,
                    const float* __restrict__ stok,   const float* __restrict__ Wemb,
                    const float* __restrict__ bemb,
                    const float* __restrict__ dWih,   const float* __restrict__ dWhh,
                    const float* __restrict__ dbih,   const float* __restrict__ dbhh,
                    const float* __restrict__ Wout,   const float* __restrict__ bout,
                    const float* __restrict__ Wseq,   const float* __restrict__ bseq,
                    const float* __restrict__ Wseq2,  const float* __restrict__ bseq2,
                    float* __restrict__ recon,
                    float* __restrict__ out_mu,
                    float* __restrict__ out_lv,
                    float* __restrict__ out_num)
{
    __shared__ float hbuf[4][16][32];
    __shared__ float cbuf[4][16][32];
    __shared__ float mubuf[4][16];
    __shared__ float x0buf[4][32];
    __shared__ float cw[524];
    // cw: 0 Wmu[64] | 64 Wlv[64] | 128 Wseq[32] | 160 bseq[32] | 192 Wseq2[32]
    //     224 Wl2h[32] | 256 bl2h[32] | 288 Wl2h2[32] | 320 bl2h2[32]
    //     352 Wout[160] | 512 bout[5] | 517 bmu | 518 blv | 519 bseq2

    const int tid = threadIdx.x;
    const int w   = tid >> 6;
    const int l   = tid & 63;
    const int u   = l & 31;
    const int bh  = l >> 5;
    const int bbase = blockIdx.x * 64 + w * 16;

    if (tid < 64){ cw[tid] = Wmu[tid]; cw[64+tid] = Wlv[tid]; }
    if (tid < 32){
        cw[128+tid] = Wseq[tid];  cw[160+tid] = bseq[tid];  cw[192+tid] = Wseq2[tid];
        cw[224+tid] = Wl2h[tid];  cw[256+tid] = bl2h[tid];
        cw[288+tid] = Wl2h2[tid]; cw[320+tid] = bl2h2[tid];
    }
    if (tid < 160) cw[352+tid] = Wout[tid];
    if (tid < 5)   cw[512+tid] = bout[tid];
    if (tid == 0){ cw[517] = bmu[0]; cw[518] = blv[0]; cw[519] = bseq2[0]; }
    __syncthreads();

    // ---- encoder weights -> VGPRs (gate rows: i=u, f=32+u, g=64+u, o=96+u) ----
    float Wg[4][32], Vg[4][5], bg[4];
    #pragma unroll
    for (int gg=0; gg<4; ++gg){
        #pragma unroll
        for (int kk=0; kk<8; ++kk){
            float4 v = *(const float4*)(eWhh + (size_t)(gg*32+u)*32 + kk*4);
            Wg[gg][kk*4+0]=v.x; Wg[gg][kk*4+1]=v.y; Wg[gg][kk*4+2]=v.z; Wg[gg][kk*4+3]=v.w;
        }
        #pragma unroll
        for (int d=0; d<5; ++d) Vg[gg][d] = eWih[(size_t)(gg*32+u)*5 + d];
        bg[gg] = ebih[gg*32+u] + ebhh[gg*32+u];
    }

    float cst[8];
    #pragma unroll
    for (int p=0; p<8; ++p){ cst[p] = 0.0f; hbuf[w][bh*8+p][u] = 0.0f; }
    __syncthreads();

    // ================= encoder LSTM (T=100) =================
    for (int t=0; t<100; ++t){
        float xv[8][5];
        #pragma unroll
        for (int p=0; p<8; ++p){
            const float* xp = x + (size_t)(bbase + bh*8 + p)*500 + t*5;
            #pragma unroll
            for (int d=0; d<5; ++d) xv[p][d] = xp[d];
        }
        float gi[8], gf[8], gG[8], go[8];
        #pragma unroll
        for (int p=0; p<8; ++p){ gi[p]=bg[0]; gf[p]=bg[1]; gG[p]=bg[2]; go[p]=bg[3]; }
        #pragma unroll
        for (int p=0; p<8; ++p){
            const int r = bh*8 + p;
            #pragma unroll
            for (int kk=0; kk<8; ++kk){
                float4 h4 = *(const float4*)&hbuf[w][r][kk*4];
                const float he[4] = {h4.x, h4.y, h4.z, h4.w};
                #pragma unroll
                for (int e=0; e<4; ++e){
                    const int k = kk*4 + e;
                    gi[p] += Wg[0][k]*he[e];
                    gf[p] += Wg[1][k]*he[e];
                    gG[p] += Wg[2][k]*he[e];
                    go[p] += Wg[3][k]*he[e];
                }
            }
            #pragma unroll
            for (int d=0; d<5; ++d){
                gi[p] += Vg[0][d]*xv[p][d];
                gf[p] += Vg[1][d]*xv[p][d];
                gG[p] += Vg[2][d]*xv[p][d];
                go[p] += Vg[3][d]*xv[p][d];
            }
        }
        float hnew[8];
        #pragma unroll
        for (int p=0; p<8; ++p){
            float cn = sigm(gf[p])*cst[p] + sigm(gi[p])*tanh_(gG[p]);
            cst[p] = cn;
            hnew[p] = sigm(go[p])*tanh_(cn);
        }
        __syncthreads();
        #pragma unroll
        for (int p=0; p<8; ++p) hbuf[w][bh*8+p][u] = hnew[p];
        __syncthreads();
    }

    #pragma unroll
    for (int p=0; p<8; ++p) cbuf[w][bh*8+p][u] = cst[p];
    __syncthreads();

    // ---- decoder weights -> VGPRs ----
    float WgD[4][32], VgD[4][32], bgD[4];
    #pragma unroll
    for (int gg=0; gg<4; ++gg){
        #pragma unroll
        for (int kk=0; kk<8; ++kk){
            float4 a = *(const float4*)(dWhh + (size_t)(gg*32+u)*32 + kk*4);
            WgD[gg][kk*4+0]=a.x; WgD[gg][kk*4+1]=a.y; WgD[gg][kk*4+2]=a.z; WgD[gg][kk*4+3]=a.w;
            float4 b = *(const float4*)(dWih + (size_t)(gg*32+u)*32 + kk*4);
            VgD[gg][kk*4+0]=b.x; VgD[gg][kk*4+1]=b.y; VgD[gg][kk*4+2]=b.z; VgD[gg][kk*4+3]=b.w;
        }
        bgD[gg] = dbih[gg*32+u] + dbhh[gg*32+u];
    }

    // ---- heads: mu / logvar / num (lanes 0..15, one batch row each) ----
    if (l < 16){
        const int r = l;
        float mu = cw[517], lv = cw[518];
        #pragma unroll
        for (int k=0; k<32; ++k){
            float hv = hbuf[w][r][k], cv = cbuf[w][r][k];
            mu += hv*cw[k]    + cv*cw[32+k];
            lv += hv*cw[64+k] + cv*cw[96+k];
        }
        out_mu[bbase+r] = mu;
        out_lv[bbase+r] = lv;
        mubuf[w][r] = mu;
        float z = mu + eps[bbase+r] * __builtin_amdgcn_exp2f(0.5f*LOG2E*lv);
        float a2 = cw[519];
        #pragma unroll
        for (int j=0; j<32; ++j){
            float s = z*cw[128+j] + cw[160+j];
            s = s > 0.0f ? s : 0.01f*s;
            a2 += cw[192+j]*s;
        }
        out_num[bbase+r] = fmaxf(a2, 0.0f);
    }
    // x0 = relu(start_token @ Wemb^T + bemb)  (batch-independent)
    if (bh == 0){
        float v = bemb[u];
        #pragma unroll
        for (int d=0; d<5; ++d) v += stok[d]*Wemb[u*5 + d];
        x0buf[w][u] = fmaxf(v, 0.0f);
    }
    __syncthreads();

    // ---- decoder init: h0/c0 = lrelu(mu*W + b) ----
    float cstD[8];
    #pragma unroll
    for (int p=0; p<8; ++p){
        const int r = bh*8 + p;
        float muv = mubuf[w][r];
        float a = muv*cw[224+u] + cw[256+u];
        float b = muv*cw[288+u] + cw[320+u];
        hbuf[w][r][u] = (a > 0.0f ? a : 0.01f*a);
        cstD[p]       = (b > 0.0f ? b : 0.01f*b);
    }
    __syncthreads();

    // ================= decoder LSTM (T=100, autoregressive) =================
    for (int t=0; t<100; ++t){
        float gi[8], gf[8], gG[8], go[8];
        #pragma unroll
        for (int p=0; p<8; ++p){ gi[p]=bgD[0]; gf[p]=bgD[1]; gG[p]=bgD[2]; go[p]=bgD[3]; }
        #pragma unroll
        for (int p=0; p<8; ++p){
            const int r = bh*8 + p;
            #pragma unroll
            for (int kk=0; kk<8; ++kk){
                float4 h4 = *(const float4*)&hbuf[w][r][kk*4];
                float4 x4;
                if (t == 0) x4 = *(const float4*)&x0buf[w][kk*4];
                else { x4.x=fmaxf(h4.x,0.f); x4.y=fmaxf(h4.y,0.f); x4.z=fmaxf(h4.z,0.f); x4.w=fmaxf(h4.w,0.f); }
                const float he[4] = {h4.x, h4.y, h4.z, h4.w};
                const float xe[4] = {x4.x, x4.y, x4.z, x4.w};
                #pragma unroll
                for (int e=0; e<4; ++e){
                    const int k = kk*4 + e;
                    gi[p] += WgD[0][k]*he[e] + VgD[0][k]*xe[e];
                    gf[p] += WgD[1][k]*he[e] + VgD[1][k]*xe[e];
                    gG[p] += WgD[2][k]*he[e] + VgD[2][k]*xe[e];
                    go[p] += WgD[3][k]*he[e] + VgD[3][k]*xe[e];
                }
            }
        }
        float hnew[8];
        #pragma unroll
        for (int p=0; p<8; ++p){
            float cn = sigm(gf[p])*cstD[p] + sigm(gi[p])*tanh_(gG[p]);
            cstD[p] = cn;
            hnew[p] = sigm(go[p])*tanh_(cn);
        }
        __syncthreads();
        #pragma unroll
        for (int p=0; p<8; ++p) hbuf[w][bh*8+p][u] = hnew[p];
        __syncthreads();

        // recon[b][t][:] = h_new @ Wout^T + bout
        #pragma unroll
        for (int s=0; s<2; ++s){
            const int idx = l + 64*s;
            if (idx < 80){
                const int r = idx / 5, d = idx - 5*r;
                float acc = cw[512+d];
                #pragma unroll
                for (int kk=0; kk<8; ++kk){
                    float4 h4 = *(const float4*)&hbuf[w][r][kk*4];
                    acc += cw[352+d*32+kk*4+0]*h4.x + cw[352+d*32+kk*4+1]*h4.y
                         + cw[352+d*32+kk*4+2]*h4.z + cw[352+d*32+kk*4+3]*h4.w;
                }
                recon[(size_t)(bbase+r)*500 + t*5 + d] = acc;
            }
        }
    }
}

extern "C" void kernel_launch(void* const* d_in, const int* in_sizes, int n_in,
                              void* d_out, int out_size, void* d_ws, size_t ws_size,
                              hipStream_t stream)
{
    (void)d_ws; (void)ws_size;
    static const int EXPECT[27] = {8192000,16384,640,4096,128,128,64,1,64,1,
                                   32,32,32,32,5,160,32,4096,4096,128,128,
                                   160,5,32,32,32,1};
    bool in_ok = (n_in == 27);
    if (in_ok) for (int i = 0; i < 27; ++i) in_ok = in_ok && (in_sizes[i] == EXPECT[i]);
    bool out_ok = (out_size == 8241152);

    float* out = (float*)d_out;
    if (!in_ok){
        marker_kernel<<<(out_size + 255)/256, 256, 0, stream>>>(out, out_size, 2.0f);
        return;
    }
    if (!out_ok){
        marker_kernel<<<(out_size + 255)/256, 256, 0, stream>>>(out, out_size, 3.0f);
        return;
    }

    const float* x     = (const float*)d_in[0];
    const float* eps   = (const float*)d_in[1];
    const float* eWih  = (const float*)d_in[2];
    const float* eWhh  = (const float*)d_in[3];
    const float* ebih  = (const float*)d_in[4];
    const float* ebhh  = (const float*)d_in[5];
    const float* Wmu   = (const float*)d_in[6];
    const float* bmu   = (const float*)d_in[7];
    const float* Wlv   = (const float*)d_in[8];
    const float* blv   = (const float*)d_in[9];
    const float* Wl2h  = (const float*)d_in[10];
    const float* bl2h  = (const float*)d_in[11];
    const float* Wl2h2 = (const float*)d_in[12];
    const float* bl2h2 = (const float*)d_in[13];
    const float* stok  = (const float*)d_in[14];
    const float* Wemb  = (const float*)d_in[15];
    const float* bemb  = (const float*)d_in[16];
    const float* dWih  = (const float*)d_in[17];
    const float* dWhh  = (const float*)d_in[18];
    const float* dbih  = (const float*)d_in[19];
    const float* dbhh  = (const float*)d_in[20];
    const float* Wout  = (const float*)d_in[21];
    const float* bout  = (const float*)d_in[22];
    const float* Wseq  = (const float*)d_in[23];
    const float* bseq  = (const float*)d_in[24];
    const float* Wseq2 = (const float*)d_in[25];
    const float* bseq2 = (const float*)d_in[26];

    float* recon  = out;                 // [16384][100][5] f32
    float* out_mu = out + 8192000;       // [16384]
    float* out_lv = out_mu + 16384;      // [16384]
    float* out_nm = out_lv + 16384;      // [16384]

    vae_f32_kernel<<<256, 256, 0, stream>>>(x, eps,
        eWih, eWhh, ebih, ebhh, Wmu, bmu, Wlv, blv,
        Wl2h, bl2h, Wl2h2, bl2h2, stok, Wemb, bemb,
        dWih, dWhh, dbih, dbhh, Wout, bout,
        Wseq, bseq, Wseq2, bseq2,
        recon, out_mu, out_lv, out_nm);
}

// Round 9
// 180.309 us; speedup vs baseline: 26.5883x; 26.5883x over previous
//
#include <hip/hip_runtime.h>
#include <hip/hip_bf16.h>

typedef short bf16x8 __attribute__((ext_vector_type(8)));
typedef float f32x4  __attribute__((ext_vector_type(4)));

#define LOG2E 1.44269504088896340736f

static __device__ __forceinline__ unsigned short f2bf(float f){
    __hip_bfloat16 h = __float2bfloat16(f);
    return __builtin_bit_cast(unsigned short, h);
}
static __device__ __forceinline__ float sigm(float x){
    return __builtin_amdgcn_rcpf(1.0f + __builtin_amdgcn_exp2f(-LOG2E * x));
}
static __device__ __forceinline__ float tanh_(float x){
    return 2.0f * __builtin_amdgcn_rcpf(1.0f + __builtin_amdgcn_exp2f(-2.0f*LOG2E*x)) - 1.0f;
}
static __device__ __forceinline__ void lds_fence(){
    asm volatile("s_waitcnt lgkmcnt(0)" ::: "memory");
}
static __device__ __forceinline__ f32x4 mfma16(bf16x8 a, bf16x8 b, f32x4 c){
    return __builtin_amdgcn_mfma_f32_16x16x32_bf16(a, b, c, 0, 0, 0);
}

__global__ void marker_kernel(float* out, int n, float v){
    int i = blockIdx.x * 256 + threadIdx.x;
    if (i < n) out[i] = v;
}

// MFMA LSTM-VAE. 1 wave = 16 batch rows (MFMA M). Weights as bf16 B-fragments
// (shared per lane-role, no spill); h fp32 in LDS, bf16-rounded into A-frags.
// Gates: D[16 batch x 128 gate-rows] = 8 MFMA-blocks x (x-term + h-term).
// Lane l: c=l&15 (A-row batch / D-col), g=l>>4 (A k-chunk / D row-group).
__global__ __launch_bounds__(256, 1)
void vae_mfma_kernel(const float* __restrict__ x,      const float* __restrict__ eps,
                     const float* __restrict__ eWih,   const float* __restrict__ eWhh,
                     const float* __restrict__ ebih,   const float* __restrict__ ebhh,
                     const float* __restrict__ Wmu,    const float* __restrict__ bmu,
                     const float* __restrict__ Wlv,    const float* __restrict__ blv,
                     const float* __restrict__ Wl2h,   const float* __restrict__ bl2h,
                     const float* __restrict__ Wl2h2,  const float* __restrict__ bl2h2,
                     const float* __restrict__ stok,   const float* __restrict__ Wemb,
                     const float* __restrict__ bemb,
                     const float* __restrict__ dWih,   const float* __restrict__ dWhh,
                     const float* __restrict__ dbih,   const float* __restrict__ dbhh,
                     const float* __restrict__ Wout,   const float* __restrict__ bout,
                     const float* __restrict__ Wseq,   const float* __restrict__ bseq,
                     const float* __restrict__ Wseq2,  const float* __restrict__ bseq2,
                     float* __restrict__ recon,
                     float* __restrict__ out_mu,
                     float* __restrict__ out_lv,
                     float* __restrict__ out_num)
{
    __shared__ float hbuf[4][16][36];   // [wave][batch row][unit], stride 36 (16B-aligned b128)
    __shared__ float cbuf[4][16][36];
    __shared__ float mubuf[4][16];
    __shared__ float x0buf[4][32];
    __shared__ float cw[524];
    // cw: 0 Wmu[64] | 64 Wlv[64] | 128 Wseq[32] | 160 bseq[32] | 192 Wseq2[32]
    //     224 Wl2h[32] | 256 bl2h[32] | 288 Wl2h2[32] | 320 bl2h2[32]
    //     352 Wout[160] | 512 bout[5] | 517 bmu | 518 blv | 519 bseq2

    const int tid = threadIdx.x;
    const int w   = tid >> 6;
    const int l   = tid & 63;
    const int c   = l & 15;
    const int g   = l >> 4;
    const int bbase = blockIdx.x * 64 + w * 16;

    if (tid < 64){ cw[tid] = Wmu[tid]; cw[64+tid] = Wlv[tid]; }
    if (tid < 32){
        cw[128+tid] = Wseq[tid];  cw[160+tid] = bseq[tid];  cw[192+tid] = Wseq2[tid];
        cw[224+tid] = Wl2h[tid];  cw[256+tid] = bl2h[tid];
        cw[288+tid] = Wl2h2[tid]; cw[320+tid] = bl2h2[tid];
    }
    if (tid < 160) cw[352+tid] = Wout[tid];
    if (tid < 5)   cw[512+tid] = bout[tid];
    if (tid == 0){ cw[517] = bmu[0]; cw[518] = blv[0]; cw[519] = bseq2[0]; }
    __syncthreads();

    // ---- encoder B-fragments: B[k][col]=W[n*16+c][g*8+j] (PyTorch [4H,K]) ----
    bf16x8 BW[8], BX[8];
    float  biasg[8];
    #pragma unroll
    for (int n=0;n<8;++n){
        bf16x8 t;
        #pragma unroll
        for (int j=0;j<8;++j) t[j] = (short)f2bf(eWhh[(size_t)(n*16+c)*32 + g*8 + j]);
        BW[n] = t;
        bf16x8 tx = (bf16x8)0;
        if (g == 0){
            #pragma unroll
            for (int j=0;j<5;++j) tx[j] = (short)f2bf(eWih[(size_t)(n*16+c)*5 + j]);
        }
        BX[n] = tx;
        biasg[n] = ebih[n*16+c] + ebhh[n*16+c];
    }

    float cs[8];
    #pragma unroll
    for (int k=0;k<8;++k) cs[k] = 0.0f;
    #pragma unroll
    for (int q=0;q<4;++q){ hbuf[w][g*4+q][c] = 0.0f; hbuf[w][g*4+q][c+16] = 0.0f; }
    lds_fence();

    // x prefetch (lanes g==0 own batch row c's 5 features)
    float4 xA = {0,0,0,0}; float xB = 0.0f;
    if (g == 0){
        const float* xp = x + (size_t)(bbase+c)*500;
        xA = *(const float4*)xp; xB = xp[4];
    }

    // ================= encoder LSTM (T=100) =================
    for (int t=0; t<100; ++t){
        bf16x8 ax = (bf16x8)0;
        if (g == 0){
            ax[0]=(short)f2bf(xA.x); ax[1]=(short)f2bf(xA.y);
            ax[2]=(short)f2bf(xA.z); ax[3]=(short)f2bf(xA.w);
            ax[4]=(short)f2bf(xB);
        }
        if (g == 0 && t < 99){           // prefetch next step (hidden under compute)
            const float* xp = x + (size_t)(bbase+c)*500 + (t+1)*5;
            xA = *(const float4*)xp; xB = xp[4];
        }

        float hv[8];
        *(f32x4*)&hv[0] = *(const f32x4*)&hbuf[w][c][g*8];
        *(f32x4*)&hv[4] = *(const f32x4*)&hbuf[w][c][g*8 + 4];
        bf16x8 ah;
        #pragma unroll
        for (int j=0;j<8;++j) ah[j] = (short)f2bf(hv[j]);

        f32x4 acc[8];
        #pragma unroll
        for (int n=0;n<8;++n){
            f32x4 a; a[0]=a[1]=a[2]=a[3]=biasg[n];
            a = mfma16(ax, BX[n], a);
            a = mfma16(ah, BW[n], a);
            acc[n] = a;
        }

        float hn[8];
        #pragma unroll
        for (int u=0;u<2;++u){
          #pragma unroll
          for (int q=0;q<4;++q){
            float iv = acc[0+u][q], fv = acc[2+u][q], gv = acc[4+u][q], ov = acc[6+u][q];
            float cn  = sigm(fv)*cs[u*4+q] + sigm(iv)*tanh_(gv);
            float hvv = sigm(ov)*tanh_(cn);
            cs[u*4+q] = cn; hn[u*4+q] = hvv;
          }
        }
        #pragma unroll
        for (int q=0;q<4;++q){
            hbuf[w][g*4+q][c]    = hn[q];     // unit c,    row g*4+q
            hbuf[w][g*4+q][c+16] = hn[4+q];   // unit 16+c
        }
        lds_fence();
    }

    #pragma unroll
    for (int q=0;q<4;++q){
        cbuf[w][g*4+q][c]    = cs[q];
        cbuf[w][g*4+q][c+16] = cs[4+q];
    }
    lds_fence();

    // ---- decoder B-fragments ----
    bf16x8 BI[8], BH[8];
    float dbias[8];
    #pragma unroll
    for (int n=0;n<8;++n){
        bf16x8 ti, th;
        #pragma unroll
        for (int j=0;j<8;++j){
            ti[j] = (short)f2bf(dWih[(size_t)(n*16+c)*32 + g*8 + j]);
            th[j] = (short)f2bf(dWhh[(size_t)(n*16+c)*32 + g*8 + j]);
        }
        BI[n] = ti; BH[n] = th;
        dbias[n] = dbih[n*16+c] + dbhh[n*16+c];
    }
    bf16x8 BO = (bf16x8)0;
    float bos = 0.0f;
    if (c < 5){
        bf16x8 to;
        #pragma unroll
        for (int j=0;j<8;++j) to[j] = (short)f2bf(Wout[c*32 + g*8 + j]);
        BO = to;
        bos = bout[c];
    }

    // ---- heads: mu / logvar / num (lanes 0..15, one batch row each), fp32 ----
    if (l < 16){
        const int r = l;
        float mu = cw[517], lv = cw[518];
        #pragma unroll
        for (int k=0;k<32;++k){
            float hvv = hbuf[w][r][k], cvv = cbuf[w][r][k];
            mu += hvv*cw[k]    + cvv*cw[32+k];
            lv += hvv*cw[64+k] + cvv*cw[96+k];
        }
        out_mu[bbase+r] = mu;
        out_lv[bbase+r] = lv;
        mubuf[w][r] = mu;
        float z = mu + eps[bbase+r] * __builtin_amdgcn_exp2f(0.5f*LOG2E*lv);
        float a2 = cw[519];
        #pragma unroll
        for (int j=0;j<32;++j){
            float s = z*cw[128+j] + cw[160+j];
            s = s > 0.0f ? s : 0.01f*s;
            a2 += cw[192+j]*s;
        }
        out_num[bbase+r] = fmaxf(a2, 0.0f);
    }
    // x0 = relu(start_token @ Wemb^T + bemb), batch-independent (lanes 0..31)
    if (l < 32){
        float v = bemb[l];
        #pragma unroll
        for (int d=0; d<5; ++d) v += stok[d]*Wemb[l*5 + d];
        x0buf[w][l] = fmaxf(v, 0.0f);
    }
    lds_fence();

    // ---- decoder init: h0/c0 = lrelu(mu*W + b), written per-lane slots ----
    #pragma unroll
    for (int u=0;u<2;++u){
      #pragma unroll
      for (int q=0;q<4;++q){
        const int unit = u*16 + c;
        const int row  = g*4 + q;
        float muv = mubuf[w][row];
        float a = muv*cw[224+unit] + cw[256+unit];
        float b = muv*cw[288+unit] + cw[320+unit];
        hbuf[w][row][unit] = (a > 0.0f ? a : 0.01f*a);
        cs[u*4+q]          = (b > 0.0f ? b : 0.01f*b);
      }
    }
    lds_fence();

    bf16x8 ax0;
    #pragma unroll
    for (int j=0;j<8;++j) ax0[j] = (short)f2bf(x0buf[w][g*8 + j]);

    // ================= decoder LSTM (T=100, autoregressive) =================
    for (int t=0; t<100; ++t){
        float hv[8];
        *(f32x4*)&hv[0] = *(const f32x4*)&hbuf[w][c][g*8];
        *(f32x4*)&hv[4] = *(const f32x4*)&hbuf[w][c][g*8 + 4];
        bf16x8 ah, ar;
        #pragma unroll
        for (int j=0;j<8;++j){
            ah[j] = (short)f2bf(hv[j]);
            ar[j] = (short)f2bf(hv[j] > 0.0f ? hv[j] : 0.0f);
        }

        if (t > 0){   // recon row t-1 = h_t @ Wout^T + bout (h_t = this iter's A)
            f32x4 ao; ao[0]=ao[1]=ao[2]=ao[3]=bos;
            ao = mfma16(ah, BO, ao);
            if (c < 5){
                #pragma unroll
                for (int q=0;q<4;++q)
                    recon[(size_t)(bbase + g*4 + q)*500 + (t-1)*5 + c] = ao[q];
            }
        }

        bf16x8 ax = (t == 0) ? ax0 : ar;

        f32x4 acc[8];
        #pragma unroll
        for (int n=0;n<8;++n){
            f32x4 a; a[0]=a[1]=a[2]=a[3]=dbias[n];
            a = mfma16(ax, BI[n], a);
            a = mfma16(ah, BH[n], a);
            acc[n] = a;
        }

        float hn[8];
        #pragma unroll
        for (int u=0;u<2;++u){
          #pragma unroll
          for (int q=0;q<4;++q){
            float iv = acc[0+u][q], fv = acc[2+u][q], gv = acc[4+u][q], ov = acc[6+u][q];
            float cn  = sigm(fv)*cs[u*4+q] + sigm(iv)*tanh_(gv);
            float hvv = sigm(ov)*tanh_(cn);
            cs[u*4+q] = cn; hn[u*4+q] = hvv;
          }
        }
        #pragma unroll
        for (int q=0;q<4;++q){
            hbuf[w][g*4+q][c]    = hn[q];
            hbuf[w][g*4+q][c+16] = hn[4+q];
        }
        lds_fence();
    }

    // final recon row 99 from h_100
    {
        float hv[8];
        *(f32x4*)&hv[0] = *(const f32x4*)&hbuf[w][c][g*8];
        *(f32x4*)&hv[4] = *(const f32x4*)&hbuf[w][c][g*8 + 4];
        bf16x8 ah;
        #pragma unroll
        for (int j=0;j<8;++j) ah[j] = (short)f2bf(hv[j]);
        f32x4 ao; ao[0]=ao[1]=ao[2]=ao[3]=bos;
        ao = mfma16(ah, BO, ao);
        if (c < 5){
            #pragma unroll
            for (int q=0;q<4;++q)
                recon[(size_t)(bbase + g*4 + q)*500 + 99*5 + c] = ao[q];
        }
    }
}

extern "C" void kernel_launch(void* const* d_in, const int* in_sizes, int n_in,
                              void* d_out, int out_size, void* d_ws, size_t ws_size,
                              hipStream_t stream)
{
    (void)d_ws; (void)ws_size;
    static const int EXPECT[27] = {8192000,16384,640,4096,128,128,64,1,64,1,
                                   32,32,32,32,5,160,32,4096,4096,128,128,
                                   160,5,32,32,32,1};
    bool in_ok = (n_in == 27);
    if (in_ok) for (int i = 0; i < 27; ++i) in_ok = in_ok && (in_sizes[i] == EXPECT[i]);
    bool out_ok = (out_size == 8241152);

    float* out = (float*)d_out;
    if (!in_ok){
        marker_kernel<<<(out_size + 255)/256, 256, 0, stream>>>(out, out_size, 2.0f);
        return;
    }
    if (!out_ok){
        marker_kernel<<<(out_size + 255)/256, 256, 0, stream>>>(out, out_size, 3.0f);
        return;
    }

    const float* x     = (const float*)d_in[0];
    const float* eps   = (const float*)d_in[1];
    const float* eWih  = (const float*)d_in[2];
    const float* eWhh  = (const float*)d_in[3];
    const float* ebih  = (const float*)d_in[4];
    const float* ebhh  = (const float*)d_in[5];
    const float* Wmu   = (const float*)d_in[6];
    const float* bmu   = (const float*)d_in[7];
    const float* Wlv   = (const float*)d_in[8];
    const float* blv   = (const float*)d_in[9];
    const float* Wl2h  = (const float*)d_in[10];
    const float* bl2h  = (const float*)d_in[11];
    const float* Wl2h2 = (const float*)d_in[12];
    const float* bl2h2 = (const float*)d_in[13];
    const float* stok  = (const float*)d_in[14];
    const float* Wemb  = (const float*)d_in[15];
    const float* bemb  = (const float*)d_in[16];
    const float* dWih  = (const float*)d_in[17];
    const float* dWhh  = (const float*)d_in[18];
    const float* dbih  = (const float*)d_in[19];
    const float* dbhh  = (const float*)d_in[20];
    const float* Wout  = (const float*)d_in[21];
    const float* bout  = (const float*)d_in[22];
    const float* Wseq  = (const float*)d_in[23];
    const float* bseq  = (const float*)d_in[24];
    const float* Wseq2 = (const float*)d_in[25];
    const float* bseq2 = (const float*)d_in[26];

    float* recon  = out;                 // [16384][100][5] f32
    float* out_mu = out + 8192000;       // [16384]
    float* out_lv = out_mu + 16384;      // [16384]
    float* out_nm = out_lv + 16384;      // [16384]

    vae_mfma_kernel<<<256, 256, 0, stream>>>(x, eps,
        eWih, eWhh, ebih, ebhh, Wmu, bmu, Wlv, blv,
        Wl2h, bl2h, Wl2h2, bl2h2, stok, Wemb, bemb,
        dWih, dWhh, dbih, dbhh, Wout, bout,
        Wseq, bseq, Wseq2, bseq2,
        recon, out_mu, out_lv, out_nm);
}

// Round 11
// 154.542 us; speedup vs baseline: 31.0215x; 1.1667x over previous
//
#include <hip/hip_runtime.h>
#include <hip/hip_bf16.h>

typedef short bf16x8 __attribute__((ext_vector_type(8)));
typedef float f32x4  __attribute__((ext_vector_type(4)));
typedef unsigned int u32x4 __attribute__((ext_vector_type(4)));

#define LOG2E 1.44269504088896340736f

static __device__ __forceinline__ unsigned short f2bf(float f){
    __hip_bfloat16 h = __float2bfloat16(f);
    return __builtin_bit_cast(unsigned short, h);
}
static __device__ __forceinline__ float bf2f(unsigned short u){
    unsigned v = ((unsigned)u) << 16;
    return __builtin_bit_cast(float, v);
}
static __device__ __forceinline__ unsigned pk_bf16(float lo, float hi){
    return (((unsigned)f2bf(hi)) << 16) | (unsigned)f2bf(lo);
}
static __device__ __forceinline__ float rcp_(float x){ return __builtin_amdgcn_rcpf(x); }
static __device__ __forceinline__ float ex2(float x){ return __builtin_amdgcn_exp2f(x); }
static __device__ __forceinline__ void lds_fence(){
    asm volatile("s_waitcnt lgkmcnt(0)" ::: "memory");
}
static __device__ __forceinline__ f32x4 mfma16(bf16x8 a, bf16x8 b, f32x4 c){
    return __builtin_amdgcn_mfma_f32_16x16x32_bf16(a, b, c, 0, 0, 0);
}

__global__ void marker_kernel(float* out, int n, float v){
    int i = blockIdx.x * 256 + threadIdx.x;
    if (i < n) out[i] = v;
}

// MFMA LSTM-VAE v2. 1 wave = 16 batch rows. Gate B-fragments use an even/odd
// column permutation (col c -> gate row base+2c+parity) so each lane owns
// ADJACENT units (2c,2c+1): h packs to u32 bf16 pairs in LDS (1 b128 read, 4
// b32 writes per step, zero conversions on the A-frag read path). Weights and
// biases pre-scaled by -log2e (g-gate: -2log2e) so MFMA outputs feed exp2
// directly; c' and h each use a single rcp over a common denominator.
__global__ __launch_bounds__(256, 1)
void vae_mfma2_kernel(const float* __restrict__ x,      const float* __restrict__ eps,
                      const float* __restrict__ eWih,   const float* __restrict__ eWhh,
                      const float* __restrict__ ebih,   const float* __restrict__ ebhh,
                      const float* __restrict__ Wmu,    const float* __restrict__ bmu,
                      const float* __restrict__ Wlv,    const float* __restrict__ blv,
                      const float* __restrict__ Wl2h,   const float* __restrict__ bl2h,
                      const float* __restrict__ Wl2h2,  const float* __restrict__ bl2h2,
                      const float* __restrict__ stok,   const float* __restrict__ Wemb,
                      const float* __restrict__ bemb,
                      const float* __restrict__ dWih,   const float* __restrict__ dWhh,
                      const float* __restrict__ dbih,   const float* __restrict__ dbhh,
                      const float* __restrict__ Wout,   const float* __restrict__ bout,
                      const float* __restrict__ Wseq,   const float* __restrict__ bseq,
                      const float* __restrict__ Wseq2,  const float* __restrict__ bseq2,
                      float* __restrict__ recon,
                      float* __restrict__ out_mu,
                      float* __restrict__ out_lv,
                      float* __restrict__ out_num)
{
    __shared__ unsigned hb[4][16][20];   // packed bf16 h: [wave][row][word c], 16 data + 4 pad words
    __shared__ float cbuf[4][16][36];    // f32 c-state for heads
    __shared__ float mubuf[4][16];
    __shared__ float x0buf[4][32];
    __shared__ float cw[524];
    // cw: 0 Wmu[64] | 64 Wlv[64] | 128 Wseq[32] | 160 bseq[32] | 192 Wseq2[32]
    //     224 Wl2h[32] | 256 bl2h[32] | 288 Wl2h2[32] | 320 bl2h2[32]
    //     352 Wout[160] | 512 bout[5] | 517 bmu | 518 blv | 519 bseq2

    const int tid = threadIdx.x;
    const int w   = tid >> 6;
    const int l   = tid & 63;
    const int c   = l & 15;
    const int g   = l >> 4;
    const int bbase = blockIdx.x * 64 + w * 16;

    if (tid < 64){ cw[tid] = Wmu[tid]; cw[64+tid] = Wlv[tid]; }
    if (tid < 32){
        cw[128+tid] = Wseq[tid];  cw[160+tid] = bseq[tid];  cw[192+tid] = Wseq2[tid];
        cw[224+tid] = Wl2h[tid];  cw[256+tid] = bl2h[tid];
        cw[288+tid] = Wl2h2[tid]; cw[320+tid] = bl2h2[tid];
    }
    if (tid < 160) cw[352+tid] = Wout[tid];
    if (tid < 5)   cw[512+tid] = bout[tid];
    if (tid == 0){ cw[517] = bmu[0]; cw[518] = blv[0]; cw[519] = bseq2[0]; }
    __syncthreads();

    // ---- encoder fragments: permuted cols, pre-scaled by -log2e / -2log2e ----
    bf16x8 BW[8], BX[8];
    f32x4  biasv[8];
    #pragma unroll
    for (int n=0;n<8;++n){
        const int row = (n>>1)*32 + 2*c + (n&1);
        const float sc = (n==4||n==5) ? (-2.0f*LOG2E) : (-LOG2E);
        bf16x8 t;
        #pragma unroll
        for (int j=0;j<8;++j) t[j] = (short)f2bf(sc * eWhh[(size_t)row*32 + g*8 + j]);
        BW[n] = t;
        bf16x8 tx = (bf16x8)0;
        if (g == 0){
            #pragma unroll
            for (int j=0;j<5;++j) tx[j] = (short)f2bf(sc * eWih[(size_t)row*5 + j]);
        }
        BX[n] = tx;
        float bv = sc * (ebih[row] + ebhh[row]);
        f32x4 b4; b4[0]=b4[1]=b4[2]=b4[3]=bv;
        biasv[n] = b4;
    }

    float cs[8];
    #pragma unroll
    for (int k=0;k<8;++k) cs[k] = 0.0f;
    #pragma unroll
    for (int q=0;q<4;++q) hb[w][g*4+q][c] = 0u;
    lds_fence();

    float4 xA = {0,0,0,0}; float xB = 0.0f;
    if (g == 0){
        const float* xp = x + (size_t)(bbase+c)*500;
        xA = *(const float4*)xp; xB = xp[4];
    }

    // ================= encoder LSTM (T=100) =================
    for (int t=0; t<100; ++t){
        bf16x8 ax = (bf16x8)0;
        if (g == 0){
            ax[0]=(short)f2bf(xA.x); ax[1]=(short)f2bf(xA.y);
            ax[2]=(short)f2bf(xA.z); ax[3]=(short)f2bf(xA.w);
            ax[4]=(short)f2bf(xB);
            if (t < 99){
                const float* xp = x + (size_t)(bbase+c)*500 + (t+1)*5;
                xA = *(const float4*)xp; xB = xp[4];
            }
        }
        u32x4 av = *(const u32x4*)&hb[w][c][g*4];
        bf16x8 ah = __builtin_bit_cast(bf16x8, av);

        f32x4 acc[8];
        #pragma unroll
        for (int n=0;n<8;++n){
            f32x4 a = mfma16(ax, BX[n], biasv[n]);
            acc[n] = mfma16(ah, BW[n], a);
        }

        #pragma unroll
        for (int q=0;q<4;++q){
            float hpair[2];
            #pragma unroll
            for (int u=0;u<2;++u){
                float ei = ex2(acc[0+u][q]);      // e^{-i}
                float ef = ex2(acc[2+u][q]);      // e^{-f}
                float eg = ex2(acc[4+u][q]);      // e^{-2g}
                float eo = ex2(acc[6+u][q]);      // e^{-o}
                float pig = (1.0f+ei)*(1.0f+eg);
                float num = cs[u*4+q]*pig + (1.0f+ef)*(1.0f-eg);
                float cn  = num * rcp_((1.0f+ef)*pig);
                float ec  = ex2(cn * (-2.0f*LOG2E));
                hpair[u]  = (1.0f-ec) * rcp_((1.0f+eo)*(1.0f+ec));
                cs[u*4+q] = cn;
            }
            hb[w][g*4+q][c] = pk_bf16(hpair[0], hpair[1]);
        }
        lds_fence();
    }

    // final c -> cbuf (f32) for heads; units 2c / 2c+1
    #pragma unroll
    for (int q=0;q<4;++q){
        cbuf[w][g*4+q][2*c]   = cs[q];
        cbuf[w][g*4+q][2*c+1] = cs[4+q];
    }
    lds_fence();

    // ---- decoder fragments (permuted + scaled); issued early ----
    bf16x8 BI[8], BH[8];
    f32x4  dbias[8];
    #pragma unroll
    for (int n=0;n<8;++n){
        const int row = (n>>1)*32 + 2*c + (n&1);
        const float sc = (n==4||n==5) ? (-2.0f*LOG2E) : (-LOG2E);
        bf16x8 ti, th;
        #pragma unroll
        for (int j=0;j<8;++j){
            ti[j] = (short)f2bf(sc * dWih[(size_t)row*32 + g*8 + j]);
            th[j] = (short)f2bf(sc * dWhh[(size_t)row*32 + g*8 + j]);
        }
        BI[n] = ti; BH[n] = th;
        float bv = sc * (dbih[row] + dbhh[row]);
        f32x4 b4; b4[0]=b4[1]=b4[2]=b4[3]=bv;
        dbias[n] = b4;
    }
    bf16x8 BO = (bf16x8)0;
    f32x4 bosv; bosv[0]=bosv[1]=bosv[2]=bosv[3]=0.0f;
    if (c < 5){
        bf16x8 to;
        #pragma unroll
        for (int j=0;j<8;++j) to[j] = (short)f2bf(Wout[c*32 + g*8 + j]);
        BO = to;
        float b = bout[c];
        bosv[0]=bosv[1]=bosv[2]=bosv[3]=b;
    }

    // ---- heads: mu / logvar / num (lanes 0..15) ----
    if (l < 16){
        const int r = l;
        const unsigned short* hrow = (const unsigned short*)&hb[w][r][0];
        float mu = cw[517], lv = cw[518];
        #pragma unroll
        for (int k=0;k<32;++k){
            float hvv = bf2f(hrow[k]);
            float cvv = cbuf[w][r][k];
            mu += hvv*cw[k]    + cvv*cw[32+k];
            lv += hvv*cw[64+k] + cvv*cw[96+k];
        }
        out_mu[bbase+r] = mu;
        out_lv[bbase+r] = lv;
        mubuf[w][r] = mu;
        float z = mu + eps[bbase+r] * __builtin_amdgcn_exp2f(0.5f*LOG2E*lv);
        float a2 = cw[519];
        #pragma unroll
        for (int j=0;j<32;++j){
            float s = z*cw[128+j] + cw[160+j];
            s = s > 0.0f ? s : 0.01f*s;
            a2 += cw[192+j]*s;
        }
        out_num[bbase+r] = fmaxf(a2, 0.0f);
    }
    // x0 = relu(start_token @ Wemb^T + bemb), batch-independent
    if (l < 32){
        float v = bemb[l];
        #pragma unroll
        for (int d=0; d<5; ++d) v += stok[d]*Wemb[l*5 + d];
        x0buf[w][l] = fmaxf(v, 0.0f);
    }
    lds_fence();

    // ---- decoder init: h0/c0 = lrelu(mu*W + b), packed units 2c/2c+1 ----
    #pragma unroll
    for (int q=0;q<4;++q){
        const int row = g*4 + q;
        float muv = mubuf[w][row];
        float a0 = muv*cw[224+2*c]   + cw[256+2*c];
        float a1 = muv*cw[224+2*c+1] + cw[256+2*c+1];
        a0 = a0 > 0.0f ? a0 : 0.01f*a0;
        a1 = a1 > 0.0f ? a1 : 0.01f*a1;
        hb[w][row][c] = pk_bf16(a0, a1);
        float b0 = muv*cw[288+2*c]   + cw[320+2*c];
        float b1 = muv*cw[288+2*c+1] + cw[320+2*c+1];
        cs[q]   = b0 > 0.0f ? b0 : 0.01f*b0;
        cs[4+q] = b1 > 0.0f ? b1 : 0.01f*b1;
    }
    lds_fence();

    bf16x8 ax0;
    #pragma unroll
    for (int j=0;j<8;++j) ax0[j] = (short)f2bf(x0buf[w][g*8 + j]);

    // ================= decoder LSTM (T=100, autoregressive) =================
    for (int t=0; t<100; ++t){
        u32x4 av = *(const u32x4*)&hb[w][c][g*4];
        bf16x8 ah = __builtin_bit_cast(bf16x8, av);

        // relu on packed bf16 pairs (zero halves with sign bit set)
        u32x4 rv;
        #pragma unroll
        for (int i=0;i<4;++i){
            unsigned v = av[i];
            unsigned m = ((v >> 15) & 0x00010001u) * 0xFFFFu;
            rv[i] = v & ~m;
        }
        bf16x8 ar = __builtin_bit_cast(bf16x8, rv);

        if (t > 0){   // recon row t-1 = h_t @ Wout^T + bout
            f32x4 ao = mfma16(ah, BO, bosv);
            if (c < 5){
                #pragma unroll
                for (int q=0;q<4;++q)
                    recon[(size_t)(bbase + g*4 + q)*500 + (t-1)*5 + c] = ao[q];
            }
        }

        bf16x8 ax = (t == 0) ? ax0 : ar;

        f32x4 acc[8];
        #pragma unroll
        for (int n=0;n<8;++n){
            f32x4 a = mfma16(ax, BI[n], dbias[n]);
            acc[n] = mfma16(ah, BH[n], a);
        }

        #pragma unroll
        for (int q=0;q<4;++q){
            float hpair[2];
            #pragma unroll
            for (int u=0;u<2;++u){
                float ei = ex2(acc[0+u][q]);
                float ef = ex2(acc[2+u][q]);
                float eg = ex2(acc[4+u][q]);
                float eo = ex2(acc[6+u][q]);
                float pig = (1.0f+ei)*(1.0f+eg);
                float num = cs[u*4+q]*pig + (1.0f+ef)*(1.0f-eg);
                float cn  = num * rcp_((1.0f+ef)*pig);
                float ec  = ex2(cn * (-2.0f*LOG2E));
                hpair[u]  = (1.0f-ec) * rcp_((1.0f+eo)*(1.0f+ec));
                cs[u*4+q] = cn;
            }
            hb[w][g*4+q][c] = pk_bf16(hpair[0], hpair[1]);
        }
        lds_fence();
    }

    // final recon row 99 from h_100
    {
        u32x4 av = *(const u32x4*)&hb[w][c][g*4];
        bf16x8 ah = __builtin_bit_cast(bf16x8, av);
        f32x4 ao = mfma16(ah, BO, bosv);
        if (c < 5){
            #pragma unroll
            for (int q=0;q<4;++q)
                recon[(size_t)(bbase + g*4 + q)*500 + 99*5 + c] = ao[q];
        }
    }
}

extern "C" void kernel_launch(void* const* d_in, const int* in_sizes, int n_in,
                              void* d_out, int out_size, void* d_ws, size_t ws_size,
                              hipStream_t stream)
{
    (void)d_ws; (void)ws_size;
    static const int EXPECT[27] = {8192000,16384,640,4096,128,128,64,1,64,1,
                                   32,32,32,32,5,160,32,4096,4096,128,128,
                                   160,5,32,32,32,1};
    bool in_ok = (n_in == 27);
    if (in_ok) for (int i = 0; i < 27; ++i) in_ok = in_ok && (in_sizes[i] == EXPECT[i]);
    bool out_ok = (out_size == 8241152);

    float* out = (float*)d_out;
    if (!in_ok){
        marker_kernel<<<(out_size + 255)/256, 256, 0, stream>>>(out, out_size, 2.0f);
        return;
    }
    if (!out_ok){
        marker_kernel<<<(out_size + 255)/256, 256, 0, stream>>>(out, out_size, 3.0f);
        return;
    }

    const float* x     = (const float*)d_in[0];
    const float* eps   = (const float*)d_in[1];
    const float* eWih  = (const float*)d_in[2];
    const float* eWhh  = (const float*)d_in[3];
    const float* ebih  = (const float*)d_in[4];
    const float* ebhh  = (const float*)d_in[5];
    const float* Wmu   = (const float*)d_in[6];
    const float* bmu   = (const float*)d_in[7];
    const float* Wlv   = (const float*)d_in[8];
    const float* blv   = (const float*)d_in[9];
    const float* Wl2h  = (const float*)d_in[10];
    const float* bl2h  = (const float*)d_in[11];
    const float* Wl2h2 = (const float*)d_in[12];
    const float* bl2h2 = (const float*)d_in[13];
    const float* stok  = (const float*)d_in[14];
    const float* Wemb  = (const float*)d_in[15];
    const float* bemb  = (const float*)d_in[16];
    const float* dWih  = (const float*)d_in[17];
    const float* dWhh  = (const float*)d_in[18];
    const float* dbih  = (const float*)d_in[19];
    const float* dbhh  = (const float*)d_in[20];
    const float* Wout  = (const float*)d_in[21];
    const float* bout  = (const float*)d_in[22];
    const float* Wseq  = (const float*)d_in[23];
    const float* bseq  = (const float*)d_in[24];
    const float* Wseq2 = (const float*)d_in[25];
    const float* bseq2 = (const float*)d_in[26];

    float* recon  = out;                 // [16384][100][5] f32
    float* out_mu = out + 8192000;       // [16384]
    float* out_lv = out_mu + 16384;      // [16384]
    float* out_nm = out_lv + 16384;      // [16384]

    vae_mfma2_kernel<<<256, 256, 0, stream>>>(x, eps,
        eWih, eWhh, ebih, ebhh, Wmu, bmu, Wlv, blv,
        Wl2h, bl2h, Wl2h2, bl2h2, stok, Wemb, bemb,
        dWih, dWhh, dbih, dbhh, Wout, bout,
        Wseq, bseq, Wseq2, bseq2,
        recon, out_mu, out_lv, out_nm);
}

// Round 12
// 136.930 us; speedup vs baseline: 35.0115x; 1.1286x over previous
//
#include <hip/hip_runtime.h>
#include <hip/hip_bf16.h>

typedef short bf16x8 __attribute__((ext_vector_type(8)));
typedef float f32x4  __attribute__((ext_vector_type(4)));
typedef unsigned int u32x4 __attribute__((ext_vector_type(4)));

#define LOG2E 1.44269504088896340736f

static __device__ __forceinline__ unsigned short f2bf(float f){
    __hip_bfloat16 h = __float2bfloat16(f);
    return __builtin_bit_cast(unsigned short, h);
}
static __device__ __forceinline__ float bf2f(unsigned short u){
    unsigned v = ((unsigned)u) << 16;
    return __builtin_bit_cast(float, v);
}
static __device__ __forceinline__ unsigned pk_bf16(float lo, float hi){
    return (((unsigned)f2bf(hi)) << 16) | (unsigned)f2bf(lo);
}
static __device__ __forceinline__ float rcp_(float x){ return __builtin_amdgcn_rcpf(x); }
static __device__ __forceinline__ float ex2(float x){ return __builtin_amdgcn_exp2f(x); }
static __device__ __forceinline__ void lds_fence(){
    asm volatile("s_waitcnt lgkmcnt(0)" ::: "memory");
}
static __device__ __forceinline__ f32x4 mfma16(bf16x8 a, bf16x8 b, f32x4 c){
    return __builtin_amdgcn_mfma_f32_16x16x32_bf16(a, b, c, 0, 0, 0);
}

__global__ void marker_kernel(float* out, int n, float v){
    int i = blockIdx.x * 256 + threadIdx.x;
    if (i < n) out[i] = v;
}

// MFMA LSTM-VAE v3: register-resident recurrence (zero in-loop LDS).
// A = WEIGHTS, B = h (cols = batch). Gate-row permutation GR(n,r) =
// gt*32 + (r>>2)*8 + (n&1)*4 + (r&3) makes lane (c,g) receive gates for
// units g*8..g*8+7 of batch c -- exactly its own B-fragment for the next
// step. h lives in 4 packed-bf16 VGPRs; no cross-lane traffic in the loop.
__global__ __launch_bounds__(256, 1)
void vae_mfma3_kernel(const float* __restrict__ x,      const float* __restrict__ eps,
                      const float* __restrict__ eWih,   const float* __restrict__ eWhh,
                      const float* __restrict__ ebih,   const float* __restrict__ ebhh,
                      const float* __restrict__ Wmu,    const float* __restrict__ bmu,
                      const float* __restrict__ Wlv,    const float* __restrict__ blv,
                      const float* __restrict__ Wl2h,   const float* __restrict__ bl2h,
                      const float* __restrict__ Wl2h2,  const float* __restrict__ bl2h2,
                      const float* __restrict__ stok,   const float* __restrict__ Wemb,
                      const float* __restrict__ bemb,
                      const float* __restrict__ dWih,   const float* __restrict__ dWhh,
                      const float* __restrict__ dbih,   const float* __restrict__ dbhh,
                      const float* __restrict__ Wout,   const float* __restrict__ bout,
                      const float* __restrict__ Wseq,   const float* __restrict__ bseq,
                      const float* __restrict__ Wseq2,  const float* __restrict__ bseq2,
                      float* __restrict__ recon,
                      float* __restrict__ out_mu,
                      float* __restrict__ out_lv,
                      float* __restrict__ out_num)
{
    __shared__ float hbf[4][16][33];   // f32 h_n for heads (once)
    __shared__ float cbf[4][16][33];   // f32 c_n for heads (once)
    __shared__ float mubuf[4][16];
    __shared__ float x0buf[4][32];
    __shared__ float cw[524];
    // cw: 0 Wmu[64] | 64 Wlv[64] | 128 Wseq[32] | 160 bseq[32] | 192 Wseq2[32]
    //     224 Wl2h[32] | 256 bl2h[32] | 288 Wl2h2[32] | 320 bl2h2[32]
    //     352 Wout[160] | 512 bout[5] | 517 bmu | 518 blv | 519 bseq2

    const int tid = threadIdx.x;
    const int w   = tid >> 6;
    const int l   = tid & 63;
    const int c   = l & 15;     // batch row / A-fragment row
    const int g   = l >> 4;     // k-chunk / D row-group
    const int bbase = blockIdx.x * 64 + w * 16;

    if (tid < 64){ cw[tid] = Wmu[tid]; cw[64+tid] = Wlv[tid]; }
    if (tid < 32){
        cw[128+tid] = Wseq[tid];  cw[160+tid] = bseq[tid];  cw[192+tid] = Wseq2[tid];
        cw[224+tid] = Wl2h[tid];  cw[256+tid] = bl2h[tid];
        cw[288+tid] = Wl2h2[tid]; cw[320+tid] = bl2h2[tid];
    }
    if (tid < 160) cw[352+tid] = Wout[tid];
    if (tid < 5)   cw[512+tid] = bout[tid];
    if (tid == 0){ cw[517] = bmu[0]; cw[518] = blv[0]; cw[519] = bseq2[0]; }
    __syncthreads();

    // ---- encoder fragments: A = W with gate-row permutation, pre-scaled ----
    bf16x8 WH[8], WX[8];
    f32x4  biasv[8];
    #pragma unroll
    for (int n=0;n<8;++n){
        const int gt = n>>1, half = n&1;
        const float sc = (gt==2) ? (-2.0f*LOG2E) : (-LOG2E);
        const int GRc = gt*32 + ((c>>2)<<3) + half*4 + (c&3);
        bf16x8 t;
        #pragma unroll
        for (int j=0;j<8;++j) t[j] = (short)f2bf(sc * eWhh[(size_t)GRc*32 + g*8 + j]);
        WH[n] = t;
        bf16x8 tx = (bf16x8)0;
        if (g == 0){
            #pragma unroll
            for (int j=0;j<5;++j) tx[j] = (short)f2bf(sc * eWih[(size_t)GRc*5 + j]);
        }
        WX[n] = tx;
        f32x4 b4;
        #pragma unroll
        for (int q=0;q<4;++q){
            const int R = gt*32 + g*8 + half*4 + q;
            b4[q] = sc * (ebih[R] + ebhh[R]);
        }
        biasv[n] = b4;
    }

    float cs[8], hn[8];
    #pragma unroll
    for (int k=0;k<8;++k){ cs[k] = 0.0f; hn[k] = 0.0f; }
    u32x4 hpk = (u32x4)0;            // packed bf16 h: word w = units (g*8+2w, g*8+2w+1) of batch c

    float4 xA = {0,0,0,0}; float xB = 0.0f;
    if (g == 0){
        const float* xp = x + (size_t)(bbase+c)*500;
        xA = *(const float4*)xp; xB = xp[4];
    }

    // ================= encoder LSTM (T=100), register-only recurrence =================
    for (int t=0; t<100; ++t){
        bf16x8 bx = (bf16x8)0;
        if (g == 0){
            bx[0]=(short)f2bf(xA.x); bx[1]=(short)f2bf(xA.y);
            bx[2]=(short)f2bf(xA.z); bx[3]=(short)f2bf(xA.w);
            bx[4]=(short)f2bf(xB);
            if (t < 99){
                const float* xp = x + (size_t)(bbase+c)*500 + (t+1)*5;
                xA = *(const float4*)xp; xB = xp[4];
            }
        }
        bf16x8 bh = __builtin_bit_cast(bf16x8, hpk);

        f32x4 acc[8];
        #pragma unroll
        for (int n=0;n<8;++n){
            f32x4 a = mfma16(WX[n], bx, biasv[n]);
            acc[n] = mfma16(WH[n], bh, a);
        }

        #pragma unroll
        for (int q=0;q<4;++q){
          #pragma unroll
          for (int u=0;u<2;++u){
            const int ul = u*4 + q;
            float ei = ex2(acc[0+u][q]);      // e^{-i}
            float ef = ex2(acc[2+u][q]);      // e^{-f}
            float eg = ex2(acc[4+u][q]);      // e^{-2g}
            float eo = ex2(acc[6+u][q]);      // e^{-o}
            float pig = (1.0f+ei)*(1.0f+eg);
            float num = cs[ul]*pig + (1.0f+ef)*(1.0f-eg);
            float cn  = num * rcp_((1.0f+ef)*pig);
            float ec  = ex2(cn * (-2.0f*LOG2E));
            hn[ul]    = (1.0f-ec) * rcp_((1.0f+eo)*(1.0f+ec));
            cs[ul]    = cn;
          }
        }
        hpk[0] = pk_bf16(hn[0], hn[1]);
        hpk[1] = pk_bf16(hn[2], hn[3]);
        hpk[2] = pk_bf16(hn[4], hn[5]);
        hpk[3] = pk_bf16(hn[6], hn[7]);
    }

    // ---- h_n / c_n to LDS for the heads (once) ----
    #pragma unroll
    for (int ul=0; ul<8; ++ul){
        hbf[w][c][g*8+ul] = hn[ul];
        cbf[w][c][g*8+ul] = cs[ul];
    }
    lds_fence();

    // ---- decoder fragments (loaded now; heads below hide latency) ----
    bf16x8 WI[8], WHd[8];
    f32x4  dbias[8];
    #pragma unroll
    for (int n=0;n<8;++n){
        const int gt = n>>1, half = n&1;
        const float sc = (gt==2) ? (-2.0f*LOG2E) : (-LOG2E);
        const int GRc = gt*32 + ((c>>2)<<3) + half*4 + (c&3);
        bf16x8 ti, th;
        #pragma unroll
        for (int j=0;j<8;++j){
            ti[j] = (short)f2bf(sc * dWih[(size_t)GRc*32 + g*8 + j]);
            th[j] = (short)f2bf(sc * dWhh[(size_t)GRc*32 + g*8 + j]);
        }
        WI[n] = ti; WHd[n] = th;
        f32x4 b4;
        #pragma unroll
        for (int q=0;q<4;++q){
            const int R = gt*32 + g*8 + half*4 + q;
            b4[q] = sc * (dbih[R] + dbhh[R]);
        }
        dbias[n] = b4;
    }
    bf16x8 WO = (bf16x8)0;
    f32x4 bosv = (f32x4)0;
    if (c < 5){
        bf16x8 to;
        #pragma unroll
        for (int j=0;j<8;++j) to[j] = (short)f2bf(Wout[c*32 + g*8 + j]);
        WO = to;
    }
    #pragma unroll
    for (int q=0;q<4;++q){
        const int dd = g*4 + q;
        bosv[q] = (dd < 5) ? bout[dd] : 0.0f;
    }

    // ---- heads: mu / logvar / num (lanes 0..15, one batch row each) ----
    if (l < 16){
        const int r = l;
        float mu = cw[517], lv = cw[518];
        #pragma unroll
        for (int k=0;k<32;++k){
            float hvv = hbf[w][r][k], cvv = cbf[w][r][k];
            mu += hvv*cw[k]    + cvv*cw[32+k];
            lv += hvv*cw[64+k] + cvv*cw[96+k];
        }
        out_mu[bbase+r] = mu;
        out_lv[bbase+r] = lv;
        mubuf[w][r] = mu;
        float z = mu + eps[bbase+r] * __builtin_amdgcn_exp2f(0.5f*LOG2E*lv);
        float a2 = cw[519];
        #pragma unroll
        for (int j=0;j<32;++j){
            float s = z*cw[128+j] + cw[160+j];
            s = s > 0.0f ? s : 0.01f*s;
            a2 += cw[192+j]*s;
        }
        out_num[bbase+r] = fmaxf(a2, 0.0f);
    }
    // x0 = relu(start_token @ Wemb^T + bemb), batch-independent
    if (l < 32){
        float v = bemb[l];
        #pragma unroll
        for (int d=0; d<5; ++d) v += stok[d]*Wemb[l*5 + d];
        x0buf[w][l] = fmaxf(v, 0.0f);
    }
    lds_fence();

    // ---- decoder init: h0/c0 = lrelu(mu*W + b) for units g*8+ul of batch c ----
    {
        const float muv = mubuf[w][c];
        #pragma unroll
        for (int ul=0; ul<8; ++ul){
            const int U = g*8 + ul;
            float a = muv*cw[224+U] + cw[256+U];
            float b = muv*cw[288+U] + cw[320+U];
            hn[ul] = (a > 0.0f ? a : 0.01f*a);
            cs[ul] = (b > 0.0f ? b : 0.01f*b);
        }
        hpk[0] = pk_bf16(hn[0], hn[1]);
        hpk[1] = pk_bf16(hn[2], hn[3]);
        hpk[2] = pk_bf16(hn[4], hn[5]);
        hpk[3] = pk_bf16(hn[6], hn[7]);
    }
    bf16x8 bx0;
    #pragma unroll
    for (int j=0;j<8;++j) bx0[j] = (short)f2bf(x0buf[w][g*8 + j]);

    // ================= decoder LSTM (T=100, autoregressive, register-only) =================
    for (int t=0; t<100; ++t){
        bf16x8 bh = __builtin_bit_cast(bf16x8, hpk);

        if (t > 0){   // recon row t-1 = Wout @ h_t (D: row=dim g*4+q, col=batch c)
            f32x4 ao = mfma16(WO, bh, bosv);
            float* rp = recon + (size_t)(bbase+c)*500 + (t-1)*5;
            if (g == 0){ rp[0]=ao[0]; rp[1]=ao[1]; rp[2]=ao[2]; rp[3]=ao[3]; }
            else if (g == 1){ rp[4]=ao[0]; }
        }

        bf16x8 bx;
        if (t == 0) bx = bx0;
        else {
            u32x4 rv;
            #pragma unroll
            for (int i=0;i<4;++i){
                unsigned v = hpk[i];
                unsigned m = ((v >> 15) & 0x00010001u) * 0xFFFFu;
                rv[i] = v & ~m;          // relu on packed bf16 pairs
            }
            bx = __builtin_bit_cast(bf16x8, rv);
        }

        f32x4 acc[8];
        #pragma unroll
        for (int n=0;n<8;++n){
            f32x4 a = mfma16(WI[n], bx, dbias[n]);
            acc[n] = mfma16(WHd[n], bh, a);
        }

        #pragma unroll
        for (int q=0;q<4;++q){
          #pragma unroll
          for (int u=0;u<2;++u){
            const int ul = u*4 + q;
            float ei = ex2(acc[0+u][q]);
            float ef = ex2(acc[2+u][q]);
            float eg = ex2(acc[4+u][q]);
            float eo = ex2(acc[6+u][q]);
            float pig = (1.0f+ei)*(1.0f+eg);
            float num = cs[ul]*pig + (1.0f+ef)*(1.0f-eg);
            float cn  = num * rcp_((1.0f+ef)*pig);
            float ec  = ex2(cn * (-2.0f*LOG2E));
            hn[ul]    = (1.0f-ec) * rcp_((1.0f+eo)*(1.0f+ec));
            cs[ul]    = cn;
          }
        }
        hpk[0] = pk_bf16(hn[0], hn[1]);
        hpk[1] = pk_bf16(hn[2], hn[3]);
        hpk[2] = pk_bf16(hn[4], hn[5]);
        hpk[3] = pk_bf16(hn[6], hn[7]);
    }

    // final recon row 99 from h_100
    {
        bf16x8 bh = __builtin_bit_cast(bf16x8, hpk);
        f32x4 ao = mfma16(WO, bh, bosv);
        float* rp = recon + (size_t)(bbase+c)*500 + 99*5;
        if (g == 0){ rp[0]=ao[0]; rp[1]=ao[1]; rp[2]=ao[2]; rp[3]=ao[3]; }
        else if (g == 1){ rp[4]=ao[0]; }
    }
}

extern "C" void kernel_launch(void* const* d_in, const int* in_sizes, int n_in,
                              void* d_out, int out_size, void* d_ws, size_t ws_size,
                              hipStream_t stream)
{
    (void)d_ws; (void)ws_size;
    static const int EXPECT[27] = {8192000,16384,640,4096,128,128,64,1,64,1,
                                   32,32,32,32,5,160,32,4096,4096,128,128,
                                   160,5,32,32,32,1};
    bool in_ok = (n_in == 27);
    if (in_ok) for (int i = 0; i < 27; ++i) in_ok = in_ok && (in_sizes[i] == EXPECT[i]);
    bool out_ok = (out_size == 8241152);

    float* out = (float*)d_out;
    if (!in_ok){
        marker_kernel<<<(out_size + 255)/256, 256, 0, stream>>>(out, out_size, 2.0f);
        return;
    }
    if (!out_ok){
        marker_kernel<<<(out_size + 255)/256, 256, 0, stream>>>(out, out_size, 3.0f);
        return;
    }

    const float* x     = (const float*)d_in[0];
    const float* eps   = (const float*)d_in[1];
    const float* eWih  = (const float*)d_in[2];
    const float* eWhh  = (const float*)d_in[3];
    const float* ebih  = (const float*)d_in[4];
    const float* ebhh  = (const float*)d_in[5];
    const float* Wmu   = (const float*)d_in[6];
    const float* bmu   = (const float*)d_in[7];
    const float* Wlv   = (const float*)d_in[8];
    const float* blv   = (const float*)d_in[9];
    const float* Wl2h  = (const float*)d_in[10];
    const float* bl2h  = (const float*)d_in[11];
    const float* Wl2h2 = (const float*)d_in[12];
    const float* bl2h2 = (const float*)d_in[13];
    const float* stok  = (const float*)d_in[14];
    const float* Wemb  = (const float*)d_in[15];
    const float* bemb  = (const float*)d_in[16];
    const float* dWih  = (const float*)d_in[17];
    const float* dWhh  = (const float*)d_in[18];
    const float* dbih  = (const float*)d_in[19];
    const float* dbhh  = (const float*)d_in[20];
    const float* Wout  = (const float*)d_in[21];
    const float* bout  = (const float*)d_in[22];
    const float* Wseq  = (const float*)d_in[23];
    const float* bseq  = (const float*)d_in[24];
    const float* Wseq2 = (const float*)d_in[25];
    const float* bseq2 = (const float*)d_in[26];

    float* recon  = out;                 // [16384][100][5] f32
    float* out_mu = out + 8192000;       // [16384]
    float* out_lv = out_mu + 16384;      // [16384]
    float* out_nm = out_lv + 16384;      // [16384]

    vae_mfma3_kernel<<<256, 256, 0, stream>>>(x, eps,
        eWih, eWhh, ebih, ebhh, Wmu, bmu, Wlv, blv,
        Wl2h, bl2h, Wl2h2, bl2h2, stok, Wemb, bemb,
        dWih, dWhh, dbih, dbhh, Wout, bout,
        Wseq, bseq, Wseq2, bseq2,
        recon, out_mu, out_lv, out_nm);
}